// Round 1
// baseline (3625.076 us; speedup 1.0000x reference)
//
#include <hip/hip_runtime.h>
#include <stdint.h>

#define B_    128
#define S_    256
#define EMB_  300
#define HID_  256
#define TAGS_ 50
#define KPAD  320           // EMB padded to multiple of 32
#define NROWS (B_ * S_)     // 32768, row r = s*128 + b
#define GF    (4 * HID_)    // 1024 gate cols per direction
#define NCOLS (2 * GF)      // 2048 (fwd | bwd)

typedef __bf16 bf16x8 __attribute__((ext_vector_type(8)));
typedef float  f32x4  __attribute__((ext_vector_type(4)));
typedef unsigned int u32x4 __attribute__((ext_vector_type(4)));
typedef unsigned int u32x2 __attribute__((ext_vector_type(2)));

__device__ __forceinline__ unsigned short f2bf(float f) {
    unsigned int u = __float_as_uint(f);
    unsigned int r = (u + 0x7fffu + ((u >> 16) & 1u)) >> 16;  // RNE
    return (unsigned short)r;
}
__device__ __forceinline__ float bf2f(unsigned int lo16) {
    return __uint_as_float(lo16 << 16);
}
__device__ __forceinline__ bf16x8 ldb8(const unsigned short* p) {
    u32x4 v = *reinterpret_cast<const u32x4*>(p);
    return __builtin_bit_cast(bf16x8, v);
}
__device__ __forceinline__ float sigmoidf_fast(float x) {
    return 1.0f / (1.0f + __expf(-x));
}

// ---------------- K0a: embedding gather -> bf16, K-padded -------------------
__global__ void k_gather_x(const int* __restrict__ tokens, const float* __restrict__ emb,
                           unsigned short* __restrict__ X16) {
    int r = blockIdx.x;            // r = s*128 + b
    int k = threadIdx.x;           // 0..319
    int b = r & 127, s = r >> 7;
    int tok = tokens[b * S_ + s];
    float v = (k < EMB_) ? emb[(long)tok * EMB_ + k] : 0.0f;
    X16[(long)r * KPAD + k] = f2bf(v);
}

// ---------------- K0b: Wx (f|b) -> transposed bf16 [2048][320] --------------
__global__ void k_prep_w(const float* __restrict__ Wx_f, const float* __restrict__ Wx_b,
                         unsigned short* __restrict__ W16T) {
    int c = blockIdx.x;            // 0..2047
    int k = threadIdx.x;           // 0..319
    float v = 0.0f;
    if (k < EMB_) v = (c < GF) ? Wx_f[k * GF + c] : Wx_b[k * GF + (c - GF)];
    W16T[c * KPAD + k] = f2bf(v);
}

// ---------------- K0c: Wd -> transposed bf16 [64][512] ----------------------
__global__ void k_prep_wd(const float* __restrict__ Wd, unsigned short* __restrict__ WdT16) {
    int c = blockIdx.x;            // 0..63
    int k = threadIdx.x;           // 0..511
    float v = (c < TAGS_) ? Wd[k * TAGS_ + c] : 0.0f;
    WdT16[c * 512 + k] = f2bf(v);
}

// ---------------- K1: xz = X @ Wx + b  (MFMA, LDS-free) ---------------------
// C[32768][2048], tile 128x128 per block, 4 waves split M (32 rows each).
__global__ __launch_bounds__(256) void k_gemm_xz(
    const unsigned short* __restrict__ X16, const unsigned short* __restrict__ W16T,
    const float* __restrict__ b_f, const float* __restrict__ b_b,
    unsigned short* __restrict__ xz16) {
    int w = threadIdx.x >> 6, lane = threadIdx.x & 63;
    int quad = lane >> 4, l16 = lane & 15;
    int m0 = blockIdx.x * 128 + w * 32;
    int n0 = blockIdx.y * 128;
    f32x4 acc[2][8];
#pragma unroll
    for (int mt = 0; mt < 2; ++mt)
#pragma unroll
        for (int nt = 0; nt < 8; ++nt) acc[mt][nt] = (f32x4){0.f, 0.f, 0.f, 0.f};

    int koff = quad * 8;
#pragma unroll
    for (int ks = 0; ks < 10; ++ks) {
        int k0 = ks * 32 + koff;
        bf16x8 a[2], bb[8];
#pragma unroll
        for (int mt = 0; mt < 2; ++mt)
            a[mt] = ldb8(X16 + (long)(m0 + mt * 16 + l16) * KPAD + k0);
#pragma unroll
        for (int nt = 0; nt < 8; ++nt)
            bb[nt] = ldb8(W16T + (long)(n0 + nt * 16 + l16) * KPAD + k0);
#pragma unroll
        for (int mt = 0; mt < 2; ++mt)
#pragma unroll
            for (int nt = 0; nt < 8; ++nt)
                acc[mt][nt] = __builtin_amdgcn_mfma_f32_16x16x32_bf16(a[mt], bb[nt], acc[mt][nt], 0, 0, 0);
    }
#pragma unroll
    for (int mt = 0; mt < 2; ++mt)
#pragma unroll
        for (int nt = 0; nt < 8; ++nt) {
            int col = n0 + nt * 16 + l16;
            float bias = (col < GF) ? b_f[col] : b_b[col - GF];
            int rbase = m0 + mt * 16 + quad * 4;
#pragma unroll
            for (int r = 0; r < 4; ++r)
                xz16[(long)(rbase + r) * NCOLS + col] = f2bf(acc[mt][nt][r] + bias);
        }
}

// ---------------- K2: bidirectional LSTM recurrence (fp32 vector) -----------
// 64 blocks: blocks 0..31 forward (4 batches each), 32..63 backward.
__global__ __launch_bounds__(256) void k_recurrence(
    const float* __restrict__ Wh_f, const float* __restrict__ Wh_b,
    const unsigned short* __restrict__ xz16, unsigned short* __restrict__ hcat16) {
    int tid = threadIdx.x;
    int dir = blockIdx.x >> 5;
    int b0 = (blockIdx.x & 31) * 4;
    const f32x4* Wh4 = reinterpret_cast<const f32x4*>(dir ? Wh_b : Wh_f);  // [256 k][256 col4]

    __shared__ __align__(16) float h_s[4][256];
    __shared__ __align__(16) float z_s[4][1024];
    float c_reg[4] = {0.f, 0.f, 0.f, 0.f};
#pragma unroll
    for (int bi = 0; bi < 4; ++bi) h_s[bi][tid] = 0.0f;
    __syncthreads();

    for (int t = 0; t < 256; ++t) {
        int s = dir ? (255 - t) : t;
        // ---- phase A: z[bi][4 cols] = h[bi] @ Wh  (cols c0..c0+3, c0 = 4*tid)
        f32x4 acc[4];
#pragma unroll
        for (int bi = 0; bi < 4; ++bi) acc[bi] = (f32x4){0.f, 0.f, 0.f, 0.f};
        for (int k4 = 0; k4 < 64; ++k4) {
            f32x4 hv[4];
#pragma unroll
            for (int bi = 0; bi < 4; ++bi)
                hv[bi] = reinterpret_cast<const f32x4*>(h_s[bi])[k4];
#pragma unroll
            for (int kk = 0; kk < 4; ++kk) {
                f32x4 wv = Wh4[(k4 * 4 + kk) * 256 + tid];
#pragma unroll
                for (int bi = 0; bi < 4; ++bi) {
                    float hb = hv[bi][kk];
                    acc[bi] += hb * wv;
                }
            }
        }
        // add xz (bf16) and stage z in LDS
        long base = ((long)s * B_ + b0) * NCOLS + dir * GF + tid * 4;
#pragma unroll
        for (int bi = 0; bi < 4; ++bi) {
            u32x2 raw = *reinterpret_cast<const u32x2*>(xz16 + base + bi * NCOLS);
            f32x4 z;
            z[0] = acc[bi][0] + bf2f(raw[0] & 0xffffu);
            z[1] = acc[bi][1] + __uint_as_float(raw[0] & 0xffff0000u);
            z[2] = acc[bi][2] + bf2f(raw[1] & 0xffffu);
            z[3] = acc[bi][3] + __uint_as_float(raw[1] & 0xffff0000u);
            reinterpret_cast<f32x4*>(z_s[bi])[tid] = z;
        }
        __syncthreads();
        // ---- phase B: gates for hidden unit j = tid
        int j = tid;
#pragma unroll
        for (int bi = 0; bi < 4; ++bi) {
            float zi = z_s[bi][j];
            float zf = z_s[bi][256 + j];
            float zg = z_s[bi][512 + j];
            float zo = z_s[bi][768 + j];
            float si = sigmoidf_fast(zi);
            float sf = sigmoidf_fast(zf);
            float so = sigmoidf_fast(zo);
            float g  = fmaxf(zg, 0.0f);
            float c  = sf * c_reg[bi] + si * g;
            c_reg[bi] = c;
            float h = so * fmaxf(c, 0.0f);
            h_s[bi][j] = h;
            hcat16[((long)(b0 + bi) * S_ + s) * 512 + dir * HID_ + j] = f2bf(h);
        }
        __syncthreads();
    }
}

// ---------------- K3: logits = hcat @ Wd  (MFMA, N padded to 64) ------------
__global__ __launch_bounds__(256) void k_gemm_logits(
    const unsigned short* __restrict__ hcat16, const unsigned short* __restrict__ WdT16,
    float* __restrict__ logits) {
    int w = threadIdx.x >> 6, lane = threadIdx.x & 63;
    int quad = lane >> 4, l16 = lane & 15;
    int m0 = blockIdx.x * 128 + w * 32;
    f32x4 acc[2][4];
#pragma unroll
    for (int mt = 0; mt < 2; ++mt)
#pragma unroll
        for (int nt = 0; nt < 4; ++nt) acc[mt][nt] = (f32x4){0.f, 0.f, 0.f, 0.f};
#pragma unroll
    for (int ks = 0; ks < 16; ++ks) {
        int k0 = ks * 32 + quad * 8;
        bf16x8 a[2], bb[4];
#pragma unroll
        for (int mt = 0; mt < 2; ++mt)
            a[mt] = ldb8(hcat16 + (long)(m0 + mt * 16 + l16) * 512 + k0);
#pragma unroll
        for (int nt = 0; nt < 4; ++nt)
            bb[nt] = ldb8(WdT16 + (long)(nt * 16 + l16) * 512 + k0);
#pragma unroll
        for (int mt = 0; mt < 2; ++mt)
#pragma unroll
            for (int nt = 0; nt < 4; ++nt)
                acc[mt][nt] = __builtin_amdgcn_mfma_f32_16x16x32_bf16(a[mt], bb[nt], acc[mt][nt], 0, 0, 0);
    }
#pragma unroll
    for (int mt = 0; mt < 2; ++mt)
#pragma unroll
        for (int nt = 0; nt < 4; ++nt) {
            int rbase = m0 + mt * 16 + quad * 4;
            int col = nt * 16 + l16;
#pragma unroll
            for (int r = 0; r < 4; ++r)
                logits[(long)(rbase + r) * 64 + col] = acc[mt][nt][r];
        }
}

// ---------------- K4: +bd, softmax over 50 tags (one wave per row) ----------
__global__ __launch_bounds__(256) void k_softmax(const float* __restrict__ logits,
                                                 const float* __restrict__ bd,
                                                 float* __restrict__ out) {
    int w = threadIdx.x >> 6, lane = threadIdx.x & 63;
    long r = (long)blockIdx.x * 4 + w;
    float x = (lane < TAGS_) ? logits[r * 64 + lane] + bd[lane] : -3.0e38f;
    float m = x;
#pragma unroll
    for (int off = 32; off >= 1; off >>= 1) m = fmaxf(m, __shfl_xor(m, off, 64));
    float e = (lane < TAGS_) ? __expf(x - m) : 0.0f;
    float ssum = e;
#pragma unroll
    for (int off = 32; off >= 1; off >>= 1) ssum += __shfl_xor(ssum, off, 64);
    if (lane < TAGS_) out[r * TAGS_ + lane] = e / ssum;
}

extern "C" void kernel_launch(void* const* d_in, const int* in_sizes, int n_in,
                              void* d_out, int out_size, void* d_ws, size_t ws_size,
                              hipStream_t stream) {
    (void)in_sizes; (void)n_in; (void)out_size; (void)ws_size;
    const int*   tokens = (const int*)  d_in[0];
    const float* emb    = (const float*)d_in[1];
    const float* Wx_f   = (const float*)d_in[2];
    const float* Wh_f   = (const float*)d_in[3];
    const float* b_f    = (const float*)d_in[4];
    const float* Wx_b   = (const float*)d_in[5];
    const float* Wh_b   = (const float*)d_in[6];
    const float* b_b    = (const float*)d_in[7];
    const float* Wd     = (const float*)d_in[8];
    const float* bd     = (const float*)d_in[9];
    float* out = (float*)d_out;

    // workspace layout (bytes): total 190,119,936
    uint8_t* w = (uint8_t*)d_ws;
    unsigned short* X16    = (unsigned short*)(w);                  // 32768*320*2  = 20,971,520
    unsigned short* W16T   = (unsigned short*)(w + 20971520);       // 2048*320*2   =  1,310,720
    unsigned short* WdT16  = (unsigned short*)(w + 22282240);       // 64*512*2     =     65,536
    unsigned short* xz16   = (unsigned short*)(w + 22347776);       // 32768*2048*2 = 134,217,728
    unsigned short* hcat16 = (unsigned short*)(w + 156565504);      // 128*256*512*2=  33,554,432
    float*          logits = (float*)(w + 22347776);                // alias xz16 (dead after K2)

    k_gather_x <<<dim3(NROWS),      dim3(KPAD), 0, stream>>>(tokens, emb, X16);
    k_prep_w   <<<dim3(NCOLS),      dim3(KPAD), 0, stream>>>(Wx_f, Wx_b, W16T);
    k_prep_wd  <<<dim3(64),         dim3(512),  0, stream>>>(Wd, WdT16);
    k_gemm_xz  <<<dim3(256, 16),    dim3(256),  0, stream>>>(X16, W16T, b_f, b_b, xz16);
    k_recurrence<<<dim3(64),        dim3(256),  0, stream>>>(Wh_f, Wh_b, xz16, hcat16);
    k_gemm_logits<<<dim3(256),      dim3(256),  0, stream>>>(hcat16, WdT16, logits);
    k_softmax  <<<dim3(NROWS / 4),  dim3(256),  0, stream>>>(logits, bd, out);
}

// Round 3
// 1737.697 us; speedup vs baseline: 2.0861x; 2.0861x over previous
//
#include <hip/hip_runtime.h>
#include <stdint.h>

#define B_    128
#define S_    256
#define EMB_  300
#define HID_  256
#define TAGS_ 50
#define KPAD  320           // EMB padded to multiple of 32
#define NROWS (B_ * S_)     // 32768, row r = s*128 + b
#define GF    (4 * HID_)    // 1024 gate cols per direction
#define NCOLS (2 * GF)      // 2048 (fwd | bwd)

typedef __bf16 bf16x8 __attribute__((ext_vector_type(8)));
typedef float  f32x4  __attribute__((ext_vector_type(4)));
typedef unsigned int u32x4 __attribute__((ext_vector_type(4)));

__device__ __forceinline__ unsigned short f2bf(float f) {
    unsigned int u = __float_as_uint(f);
    unsigned int r = (u + 0x7fffu + ((u >> 16) & 1u)) >> 16;  // RNE
    return (unsigned short)r;
}
__device__ __forceinline__ bf16x8 ldb8(const unsigned short* p) {
    u32x4 v = *reinterpret_cast<const u32x4*>(p);
    return __builtin_bit_cast(bf16x8, v);
}
__device__ __forceinline__ float sigmoidf_fast(float x) {
    return 1.0f / (1.0f + __expf(-x));
}

// ---------------- K0a: embedding gather -> bf16, K-padded -------------------
__global__ void k_gather_x(const int* __restrict__ tokens, const float* __restrict__ emb,
                           unsigned short* __restrict__ X16) {
    int r = blockIdx.x;            // r = s*128 + b
    int k = threadIdx.x;           // 0..319
    int b = r & 127, s = r >> 7;
    int tok = tokens[b * S_ + s];
    float v = (k < EMB_) ? emb[(long)tok * EMB_ + k] : 0.0f;
    X16[(long)r * KPAD + k] = f2bf(v);
}

// ---------------- K0b: Wx (f|b) -> transposed bf16 [2048][320] --------------
__global__ void k_prep_w(const float* __restrict__ Wx_f, const float* __restrict__ Wx_b,
                         unsigned short* __restrict__ W16T) {
    int c = blockIdx.x;            // 0..2047
    int k = threadIdx.x;           // 0..319
    float v = 0.0f;
    if (k < EMB_) v = (c < GF) ? Wx_f[k * GF + c] : Wx_b[k * GF + (c - GF)];
    W16T[c * KPAD + k] = f2bf(v);
}

// ---------------- K0c: Wd -> transposed bf16 [64][512] ----------------------
__global__ void k_prep_wd(const float* __restrict__ Wd, unsigned short* __restrict__ WdT16) {
    int c = blockIdx.x;            // 0..63
    int k = threadIdx.x;           // 0..511
    float v = (c < TAGS_) ? Wd[k * TAGS_ + c] : 0.0f;
    WdT16[c * 512 + k] = f2bf(v);
}

// ---------------- K0d: Wh -> packed bf16 [2 dir][4 slice][256 c][256 k] -----
// slice sl owns hidden units j in [64*sl, 64*sl+64); c = gate*64 + jrel.
__global__ void k_prep_wh(const float* __restrict__ Wh_f, const float* __restrict__ Wh_b,
                          unsigned short* __restrict__ WhP) {
    int row = blockIdx.x;          // 0..2047 = (d*4+sl)*256 + c
    int k = threadIdx.x;           // 0..255
    int d = row >> 10, sl = (row >> 8) & 3, c = row & 255;
    int gate = c >> 6, jrel = c & 63;
    const float* Wh = d ? Wh_b : Wh_f;
    WhP[(long)row * 256 + k] = f2bf(Wh[k * GF + gate * HID_ + sl * 64 + jrel]);
}

// ---------------- K0e: zero the step counters -------------------------------
__global__ void k_zero(unsigned int* __restrict__ ctr) {
    ctr[blockIdx.x * 256 + threadIdx.x] = 0u;
}

// ---------------- K1: xz = X @ Wx + b  (MFMA, LDS-free) ---------------------
// Output written in recurrence-fragment order:
// u64 index = ((((s*16 + g16)*4 + sl)*4 + wv)*256 + lane*4 + gate
__global__ __launch_bounds__(256) void k_gemm_xz(
    const unsigned short* __restrict__ X16, const unsigned short* __restrict__ W16T,
    const float* __restrict__ b_f, const float* __restrict__ b_b,
    unsigned long long* __restrict__ xzP) {
    int w = threadIdx.x >> 6, lane = threadIdx.x & 63;
    int quad = lane >> 4, l16 = lane & 15;
    int m0 = blockIdx.x * 128 + w * 32;
    int n0 = blockIdx.y * 128;
    f32x4 acc[2][8];
#pragma unroll
    for (int mt = 0; mt < 2; ++mt)
#pragma unroll
        for (int nt = 0; nt < 8; ++nt) acc[mt][nt] = (f32x4){0.f, 0.f, 0.f, 0.f};

    int koff = quad * 8;
#pragma unroll
    for (int ks = 0; ks < 10; ++ks) {
        int k0 = ks * 32 + koff;
        bf16x8 a[2], bb[8];
#pragma unroll
        for (int mt = 0; mt < 2; ++mt)
            a[mt] = ldb8(X16 + (long)(m0 + mt * 16 + l16) * KPAD + k0);
#pragma unroll
        for (int nt = 0; nt < 8; ++nt)
            bb[nt] = ldb8(W16T + (long)(n0 + nt * 16 + l16) * KPAD + k0);
#pragma unroll
        for (int mt = 0; mt < 2; ++mt)
#pragma unroll
            for (int nt = 0; nt < 8; ++nt)
                acc[mt][nt] = __builtin_amdgcn_mfma_f32_16x16x32_bf16(a[mt], bb[nt], acc[mt][nt], 0, 0, 0);
    }
    int s = blockIdx.x;            // m>>7
#pragma unroll
    for (int mt = 0; mt < 2; ++mt) {
        int grp = w * 2 + mt;      // (b>>4)
#pragma unroll
        for (int nt = 0; nt < 8; ++nt) {
            int col = n0 + nt * 16 + l16;
            int dir = col >> 10, cc = col & 1023;
            int gate = cc >> 8, j = cc & 255;
            int sl = j >> 6, wv = (j >> 4) & 3;
            float bias = dir ? b_b[cc] : b_f[cc];
            unsigned long long pk = 0;
#pragma unroll
            for (int r = 0; r < 4; ++r)
                pk |= (unsigned long long)f2bf(acc[mt][nt][r] + bias) << (16 * r);
            long idx8 = ((((long)s * 16 + (dir * 8 + grp)) * 4 + sl) * 4 + wv) * 256 + lane * 4 + gate;
            xzP[idx8] = pk;
        }
    }
}

// ---------------- K2: bidirectional LSTM recurrence -------------------------
// 64 blocks = 2 dir x 8 batch-groups(16) x 4 j-slices(64). Wh register-resident.
// Cross-block h exchange via agent-scope atomics + per-step counters.
__global__ __launch_bounds__(256, 1) void k_recurrence(
    const unsigned short* __restrict__ WhP, const unsigned long long* __restrict__ xzP,
    unsigned short* __restrict__ hcat16, unsigned long long* __restrict__ hbuf,
    unsigned int* __restrict__ ctr) {
    int tid = threadIdx.x;
    int w = tid >> 6, lane = tid & 63, quad = lane >> 4, l16 = lane & 15;
    int blk = blockIdx.x;
    int d = blk >> 5, g = (blk >> 2) & 7, sl = blk & 3;
    int g16 = d * 8 + g;

    // persistent Wh B-fragments: whf[gate][kt], 128 VGPR/lane
    bf16x8 whf[4][8];
    const unsigned short* whp = WhP + (long)((d * 4 + sl) * 256) * 256;
#pragma unroll
    for (int gate = 0; gate < 4; ++gate)
#pragma unroll
        for (int kt = 0; kt < 8; ++kt)
            whf[gate][kt] = ldb8(whp + (gate * 64 + 16 * w + l16) * 256 + kt * 32 + quad * 8);

    unsigned int* myctr = ctr + g16 * 256;                  // one counter per step
    unsigned long long* hb0 = hbuf + (long)(g16 * 2 + 0) * 1024;  // [16 b][64 u64 = 256 k bf16]
    unsigned long long* hb1 = hbuf + (long)(g16 * 2 + 1) * 1024;

    __shared__ __align__(8) unsigned short h_s[16][64];
    float c4[4] = {0.f, 0.f, 0.f, 0.f};

    int hb_b = tid >> 4, hb_ch = tid & 15;                  // h exchange role
    long hcat_base = ((long)(g * 16 + hb_b) * S_) * 512 + d * HID_ + sl * 64 + hb_ch * 4;

    for (int t = 0; t < 256; ++t) {
        int s = d ? (255 - t) : t;
        // xz fragment (issue before spin to hide latency)
        long base8 = ((((long)s * 16 + g16) * 4 + sl) * 4 + w) * 256 + lane * 4;
        u32x4 xza = *reinterpret_cast<const u32x4*>(xzP + base8);
        u32x4 xzb = *reinterpret_cast<const u32x4*>(xzP + base8 + 2);

        f32x4 acc[4];
#pragma unroll
        for (int gate = 0; gate < 4; ++gate) acc[gate] = (f32x4){0.f, 0.f, 0.f, 0.f};

        if (t > 0) {
            while (__hip_atomic_load(&myctr[t - 1], __ATOMIC_RELAXED, __HIP_MEMORY_SCOPE_AGENT) < 4u) {}
            __builtin_amdgcn_fence(__ATOMIC_ACQUIRE, "agent");
            const unsigned short* hp = reinterpret_cast<const unsigned short*>(((t & 1) ? hb0 : hb1));
#pragma unroll
            for (int kt = 0; kt < 8; ++kt) {
                bf16x8 a = ldb8(hp + l16 * 256 + kt * 32 + quad * 8);
#pragma unroll
                for (int gate = 0; gate < 4; ++gate)
                    acc[gate] = __builtin_amdgcn_mfma_f32_16x16x32_bf16(a, whf[gate][kt], acc[gate], 0, 0, 0);
            }
        }
        // gates: lane holds batches 4*quad..+3, unit j = sl*64 + 16*w + l16
        unsigned int xr[8];
        *reinterpret_cast<u32x4*>(xr) = xza;
        *reinterpret_cast<u32x4*>(xr + 4) = xzb;
#pragma unroll
        for (int r = 0; r < 4; ++r) {
            int hi = (r & 1) * 16;
            float zi = acc[0][r] + __uint_as_float(((xr[0 + (r >> 1)] >> hi) & 0xffffu) << 16);
            float zf = acc[1][r] + __uint_as_float(((xr[2 + (r >> 1)] >> hi) & 0xffffu) << 16);
            float zg = acc[2][r] + __uint_as_float(((xr[4 + (r >> 1)] >> hi) & 0xffffu) << 16);
            float zo = acc[3][r] + __uint_as_float(((xr[6 + (r >> 1)] >> hi) & 0xffffu) << 16);
            float c = sigmoidf_fast(zf) * c4[r] + sigmoidf_fast(zi) * fmaxf(zg, 0.0f);
            c4[r] = c;
            float h = sigmoidf_fast(zo) * fmaxf(c, 0.0f);
            h_s[4 * quad + r][16 * w + l16] = f2bf(h);
        }
        __syncthreads();
        // publish h-slice (2KB) + write hcat output. batch stride in hbuf = 64 u64.
        unsigned long long hv = *reinterpret_cast<unsigned long long*>(&h_s[hb_b][hb_ch * 4]);
        unsigned long long* dst = ((t & 1) ? hb1 : hb0) + hb_b * 64 + sl * 16 + hb_ch;
        __hip_atomic_store(dst, hv, __ATOMIC_RELAXED, __HIP_MEMORY_SCOPE_AGENT);
        *reinterpret_cast<unsigned long long*>(hcat16 + hcat_base + (long)s * 512) = hv;
        __syncthreads();   // drains vmcnt: all 256 threads' stores done
        if (tid == 0)
            __hip_atomic_fetch_add(&myctr[t], 1u, __ATOMIC_RELEASE, __HIP_MEMORY_SCOPE_AGENT);
    }
}

// ---------------- K3: logits = hcat @ Wd  (MFMA, N padded to 64) ------------
__global__ __launch_bounds__(256) void k_gemm_logits(
    const unsigned short* __restrict__ hcat16, const unsigned short* __restrict__ WdT16,
    float* __restrict__ logits) {
    int w = threadIdx.x >> 6, lane = threadIdx.x & 63;
    int quad = lane >> 4, l16 = lane & 15;
    int m0 = blockIdx.x * 128 + w * 32;
    f32x4 acc[2][4];
#pragma unroll
    for (int mt = 0; mt < 2; ++mt)
#pragma unroll
        for (int nt = 0; nt < 4; ++nt) acc[mt][nt] = (f32x4){0.f, 0.f, 0.f, 0.f};
#pragma unroll
    for (int ks = 0; ks < 16; ++ks) {
        int k0 = ks * 32 + quad * 8;
        bf16x8 a[2], bb[4];
#pragma unroll
        for (int mt = 0; mt < 2; ++mt)
            a[mt] = ldb8(hcat16 + (long)(m0 + mt * 16 + l16) * 512 + k0);
#pragma unroll
        for (int nt = 0; nt < 4; ++nt)
            bb[nt] = ldb8(WdT16 + (long)(nt * 16 + l16) * 512 + k0);
#pragma unroll
        for (int mt = 0; mt < 2; ++mt)
#pragma unroll
            for (int nt = 0; nt < 4; ++nt)
                acc[mt][nt] = __builtin_amdgcn_mfma_f32_16x16x32_bf16(a[mt], bb[nt], acc[mt][nt], 0, 0, 0);
    }
#pragma unroll
    for (int mt = 0; mt < 2; ++mt)
#pragma unroll
        for (int nt = 0; nt < 4; ++nt) {
            int rbase = m0 + mt * 16 + quad * 4;
            int col = nt * 16 + l16;
#pragma unroll
            for (int r = 0; r < 4; ++r)
                logits[(long)(rbase + r) * 64 + col] = acc[mt][nt][r];
        }
}

// ---------------- K4: +bd, softmax over 50 tags (one wave per row) ----------
__global__ __launch_bounds__(256) void k_softmax(const float* __restrict__ logits,
                                                 const float* __restrict__ bd,
                                                 float* __restrict__ out) {
    int w = threadIdx.x >> 6, lane = threadIdx.x & 63;
    long r = (long)blockIdx.x * 4 + w;
    float x = (lane < TAGS_) ? logits[r * 64 + lane] + bd[lane] : -3.0e38f;
    float m = x;
#pragma unroll
    for (int off = 32; off >= 1; off >>= 1) m = fmaxf(m, __shfl_xor(m, off, 64));
    float e = (lane < TAGS_) ? __expf(x - m) : 0.0f;
    float ssum = e;
#pragma unroll
    for (int off = 32; off >= 1; off >>= 1) ssum += __shfl_xor(ssum, off, 64);
    if (lane < TAGS_) out[r * TAGS_ + lane] = e / ssum;
}

extern "C" void kernel_launch(void* const* d_in, const int* in_sizes, int n_in,
                              void* d_out, int out_size, void* d_ws, size_t ws_size,
                              hipStream_t stream) {
    (void)in_sizes; (void)n_in; (void)out_size; (void)ws_size;
    const int*   tokens = (const int*)  d_in[0];
    const float* emb    = (const float*)d_in[1];
    const float* Wx_f   = (const float*)d_in[2];
    const float* Wh_f   = (const float*)d_in[3];
    const float* b_f    = (const float*)d_in[4];
    const float* Wx_b   = (const float*)d_in[5];
    const float* Wh_b   = (const float*)d_in[6];
    const float* b_b    = (const float*)d_in[7];
    const float* Wd     = (const float*)d_in[8];
    const float* bd     = (const float*)d_in[9];
    float* out = (float*)d_out;

    // workspace layout (bytes): total 190,119,936 (same as round 1)
    uint8_t* w = (uint8_t*)d_ws;
    unsigned short* X16    = (unsigned short*)(w);                  // 20,971,520 (dead after K1)
    // aliases inside X16's region, used only after K1:
    unsigned short* WhP    = (unsigned short*)(w);                  //  1,048,576
    unsigned long long* hbuf = (unsigned long long*)(w + 1048576);  //    262,144
    unsigned int*   ctr    = (unsigned int*)(w + 1310720);          //     65,536
    unsigned short* W16T   = (unsigned short*)(w + 20971520);       //  1,310,720
    unsigned short* WdT16  = (unsigned short*)(w + 22282240);       //     65,536
    unsigned long long* xzP = (unsigned long long*)(w + 22347776);  // 134,217,728
    unsigned short* hcat16 = (unsigned short*)(w + 156565504);      //  33,554,432
    float*          logits = (float*)(w + 22347776);                // alias xzP (dead after K2)

    k_gather_x  <<<dim3(NROWS),     dim3(KPAD), 0, stream>>>(tokens, emb, X16);
    k_prep_w    <<<dim3(NCOLS),     dim3(KPAD), 0, stream>>>(Wx_f, Wx_b, W16T);
    k_prep_wd   <<<dim3(64),        dim3(512),  0, stream>>>(Wd, WdT16);
    k_gemm_xz   <<<dim3(256, 16),   dim3(256),  0, stream>>>(X16, W16T, b_f, b_b, xzP);
    // X16 region now dead -> build WhP / hbuf / ctr in it
    k_prep_wh   <<<dim3(2048),      dim3(256),  0, stream>>>(Wh_f, Wh_b, WhP);
    k_zero      <<<dim3(16),        dim3(256),  0, stream>>>(ctr);
    k_recurrence<<<dim3(64),        dim3(256),  0, stream>>>(WhP, xzP, hcat16, hbuf, ctr);
    k_gemm_logits<<<dim3(256),      dim3(256),  0, stream>>>(hcat16, WdT16, logits);
    k_softmax   <<<dim3(NROWS / 4), dim3(256),  0, stream>>>(logits, bd, out);
}

// Round 4
// 1229.707 us; speedup vs baseline: 2.9479x; 1.4131x over previous
//
#include <hip/hip_runtime.h>
#include <stdint.h>

#define B_    128
#define S_    256
#define EMB_  300
#define HID_  256
#define TAGS_ 50
#define KPAD  320           // EMB padded to multiple of 32
#define NROWS (B_ * S_)     // 32768, row r = s*128 + b
#define GF    (4 * HID_)    // 1024 gate cols per direction
#define NCOLS (2 * GF)      // 2048 (fwd | bwd)

typedef __bf16 bf16x8 __attribute__((ext_vector_type(8)));
typedef float  f32x4  __attribute__((ext_vector_type(4)));
typedef unsigned int u32x4 __attribute__((ext_vector_type(4)));
typedef unsigned long long u64x2 __attribute__((ext_vector_type(2)));

__device__ __forceinline__ unsigned short f2bf(float f) {
    unsigned int u = __float_as_uint(f);
    unsigned int r = (u + 0x7fffu + ((u >> 16) & 1u)) >> 16;  // RNE
    return (unsigned short)r;
}
__device__ __forceinline__ bf16x8 ldb8(const unsigned short* p) {
    u32x4 v = *reinterpret_cast<const u32x4*>(p);
    return __builtin_bit_cast(bf16x8, v);
}
// coherent (cache-bypassing) 16B load as two relaxed agent-scope u64 atomics
__device__ __forceinline__ bf16x8 ldb8_coh(const unsigned long long* p) {
    u64x2 v;
    v[0] = __hip_atomic_load(p,     __ATOMIC_RELAXED, __HIP_MEMORY_SCOPE_AGENT);
    v[1] = __hip_atomic_load(p + 1, __ATOMIC_RELAXED, __HIP_MEMORY_SCOPE_AGENT);
    return __builtin_bit_cast(bf16x8, v);
}
__device__ __forceinline__ float sigmoidf_fast(float x) {
    return 1.0f / (1.0f + __expf(-x));
}

// ---------------- K0a: embedding gather -> bf16, K-padded -------------------
__global__ void k_gather_x(const int* __restrict__ tokens, const float* __restrict__ emb,
                           unsigned short* __restrict__ X16) {
    int r = blockIdx.x;            // r = s*128 + b
    int k = threadIdx.x;           // 0..319
    int b = r & 127, s = r >> 7;
    int tok = tokens[b * S_ + s];
    float v = (k < EMB_) ? emb[(long)tok * EMB_ + k] : 0.0f;
    X16[(long)r * KPAD + k] = f2bf(v);
}

// ---------------- K0b: Wx (f|b) -> transposed bf16 [2048][320] --------------
__global__ void k_prep_w(const float* __restrict__ Wx_f, const float* __restrict__ Wx_b,
                         unsigned short* __restrict__ W16T) {
    int c = blockIdx.x;            // 0..2047
    int k = threadIdx.x;           // 0..319
    float v = 0.0f;
    if (k < EMB_) v = (c < GF) ? Wx_f[k * GF + c] : Wx_b[k * GF + (c - GF)];
    W16T[c * KPAD + k] = f2bf(v);
}

// ---------------- K0c: Wd -> transposed bf16 [64][512] ----------------------
__global__ void k_prep_wd(const float* __restrict__ Wd, unsigned short* __restrict__ WdT16) {
    int c = blockIdx.x;            // 0..63
    int k = threadIdx.x;           // 0..511
    float v = (c < TAGS_) ? Wd[k * TAGS_ + c] : 0.0f;
    WdT16[c * 512 + k] = f2bf(v);
}

// ---------------- K0d: Wh -> packed bf16 [2 dir][4 slice][256 c][256 k] -----
// slice sl owns hidden units j in [64*sl, 64*sl+64); c = gate*64 + jrel.
__global__ void k_prep_wh(const float* __restrict__ Wh_f, const float* __restrict__ Wh_b,
                          unsigned short* __restrict__ WhP) {
    int row = blockIdx.x;          // 0..2047 = (d*4+sl)*256 + c
    int k = threadIdx.x;           // 0..255
    int d = row >> 10, sl = (row >> 8) & 3, c = row & 255;
    int gate = c >> 6, jrel = c & 63;
    const float* Wh = d ? Wh_b : Wh_f;
    WhP[(long)row * 256 + k] = f2bf(Wh[k * GF + gate * HID_ + sl * 64 + jrel]);
}

// ---------------- K0e: zero the step counters -------------------------------
__global__ void k_zero(unsigned int* __restrict__ ctr) {
    ctr[blockIdx.x * 256 + threadIdx.x] = 0u;
}

// ---------------- K1: xz = X @ Wx + b  (MFMA, LDS-free) ---------------------
// Output written in recurrence-fragment order:
// u64 index = ((((s*16 + g16)*4 + sl)*4 + wv)*256 + lane*4 + gate
__global__ __launch_bounds__(256) void k_gemm_xz(
    const unsigned short* __restrict__ X16, const unsigned short* __restrict__ W16T,
    const float* __restrict__ b_f, const float* __restrict__ b_b,
    unsigned long long* __restrict__ xzP) {
    int w = threadIdx.x >> 6, lane = threadIdx.x & 63;
    int quad = lane >> 4, l16 = lane & 15;
    int m0 = blockIdx.x * 128 + w * 32;
    int n0 = blockIdx.y * 128;
    f32x4 acc[2][8];
#pragma unroll
    for (int mt = 0; mt < 2; ++mt)
#pragma unroll
        for (int nt = 0; nt < 8; ++nt) acc[mt][nt] = (f32x4){0.f, 0.f, 0.f, 0.f};

    int koff = quad * 8;
#pragma unroll
    for (int ks = 0; ks < 10; ++ks) {
        int k0 = ks * 32 + koff;
        bf16x8 a[2], bb[8];
#pragma unroll
        for (int mt = 0; mt < 2; ++mt)
            a[mt] = ldb8(X16 + (long)(m0 + mt * 16 + l16) * KPAD + k0);
#pragma unroll
        for (int nt = 0; nt < 8; ++nt)
            bb[nt] = ldb8(W16T + (long)(n0 + nt * 16 + l16) * KPAD + k0);
#pragma unroll
        for (int mt = 0; mt < 2; ++mt)
#pragma unroll
            for (int nt = 0; nt < 8; ++nt)
                acc[mt][nt] = __builtin_amdgcn_mfma_f32_16x16x32_bf16(a[mt], bb[nt], acc[mt][nt], 0, 0, 0);
    }
    int s = blockIdx.x;            // m>>7
#pragma unroll
    for (int mt = 0; mt < 2; ++mt) {
        int grp = w * 2 + mt;      // (b>>4)
#pragma unroll
        for (int nt = 0; nt < 8; ++nt) {
            int col = n0 + nt * 16 + l16;
            int dir = col >> 10, cc = col & 1023;
            int gate = cc >> 8, j = cc & 255;
            int sl = j >> 6, wv = (j >> 4) & 3;
            float bias = dir ? b_b[cc] : b_f[cc];
            unsigned long long pk = 0;
#pragma unroll
            for (int r = 0; r < 4; ++r)
                pk |= (unsigned long long)f2bf(acc[mt][nt][r] + bias) << (16 * r);
            long idx8 = ((((long)s * 16 + (dir * 8 + grp)) * 4 + sl) * 4 + wv) * 256 + lane * 4 + gate;
            xzP[idx8] = pk;
        }
    }
}

// ---------------- K2: bidirectional LSTM recurrence -------------------------
// 64 blocks = 2 dir x 8 batch-groups(16) x 4 j-slices(64). Wh register-resident.
// Cross-block h exchange via cache-bypassing relaxed atomics; NO fences in the
// hot loop (agent acquire/release fences emit buffer_inv/buffer_wbl2 = per-step
// L2 flushes, the round-3 killer). Ordering: __syncthreads drains vmcnt before
// the relaxed counter bump; consumer loads are branch-dependent on the poll.
__global__ __launch_bounds__(256, 1) void k_recurrence(
    const unsigned short* __restrict__ WhP, const unsigned long long* __restrict__ xzP,
    unsigned short* __restrict__ hcat16, unsigned long long* __restrict__ hbuf,
    unsigned int* __restrict__ ctr) {
    int tid = threadIdx.x;
    int w = tid >> 6, lane = tid & 63, quad = lane >> 4, l16 = lane & 15;
    int blk = blockIdx.x;
    int d = blk >> 5, g = (blk >> 2) & 7, sl = blk & 3;
    int g16 = d * 8 + g;

    // persistent Wh B-fragments: whf[gate][kt], 128 VGPR/lane
    bf16x8 whf[4][8];
    const unsigned short* whp = WhP + (long)((d * 4 + sl) * 256) * 256;
#pragma unroll
    for (int gate = 0; gate < 4; ++gate)
#pragma unroll
        for (int kt = 0; kt < 8; ++kt)
            whf[gate][kt] = ldb8(whp + (gate * 64 + 16 * w + l16) * 256 + kt * 32 + quad * 8);

    unsigned int* myctr = ctr + g16 * 256;                  // one counter per step
    unsigned long long* hb0 = hbuf + (long)(g16 * 2 + 0) * 1024;  // [16 b][64 u64 = 256 k bf16]
    unsigned long long* hb1 = hbuf + (long)(g16 * 2 + 1) * 1024;

    __shared__ __align__(8) unsigned short h_s[16][64];
    float c4[4] = {0.f, 0.f, 0.f, 0.f};

    int hb_b = tid >> 4, hb_ch = tid & 15;                  // h exchange role
    long hcat_base = ((long)(g * 16 + hb_b) * S_) * 512 + d * HID_ + sl * 64 + hb_ch * 4;

    for (int t = 0; t < 256; ++t) {
        int s = d ? (255 - t) : t;
        // xz fragment (issue before spin to hide latency; plain cached loads)
        long base8 = ((((long)s * 16 + g16) * 4 + sl) * 4 + w) * 256 + lane * 4;
        u32x4 xza = *reinterpret_cast<const u32x4*>(xzP + base8);
        u32x4 xzb = *reinterpret_cast<const u32x4*>(xzP + base8 + 2);

        f32x4 acc[4];
#pragma unroll
        for (int gate = 0; gate < 4; ++gate) acc[gate] = (f32x4){0.f, 0.f, 0.f, 0.f};

        if (t > 0) {
            // one poller per wave; reconvergence releases the other 63 lanes
            if (lane == 0) {
                while (__hip_atomic_load(&myctr[t - 1], __ATOMIC_RELAXED, __HIP_MEMORY_SCOPE_AGENT) < 4u) {}
            }
            __atomic_signal_fence(__ATOMIC_SEQ_CST);  // compiler-only barrier, no cache ops
            const unsigned long long* hp = (t & 1) ? hb0 : hb1;
#pragma unroll
            for (int kt = 0; kt < 8; ++kt) {
                bf16x8 a = ldb8_coh(hp + l16 * 64 + kt * 8 + quad * 2);
#pragma unroll
                for (int gate = 0; gate < 4; ++gate)
                    acc[gate] = __builtin_amdgcn_mfma_f32_16x16x32_bf16(a, whf[gate][kt], acc[gate], 0, 0, 0);
            }
        }
        // gates: lane holds batches 4*quad..+3, unit j = sl*64 + 16*w + l16
        unsigned int xr[8];
        *reinterpret_cast<u32x4*>(xr) = xza;
        *reinterpret_cast<u32x4*>(xr + 4) = xzb;
#pragma unroll
        for (int r = 0; r < 4; ++r) {
            int hi = (r & 1) * 16;
            float zi = acc[0][r] + __uint_as_float(((xr[0 + (r >> 1)] >> hi) & 0xffffu) << 16);
            float zf = acc[1][r] + __uint_as_float(((xr[2 + (r >> 1)] >> hi) & 0xffffu) << 16);
            float zg = acc[2][r] + __uint_as_float(((xr[4 + (r >> 1)] >> hi) & 0xffffu) << 16);
            float zo = acc[3][r] + __uint_as_float(((xr[6 + (r >> 1)] >> hi) & 0xffffu) << 16);
            float c = sigmoidf_fast(zf) * c4[r] + sigmoidf_fast(zi) * fmaxf(zg, 0.0f);
            c4[r] = c;
            float h = sigmoidf_fast(zo) * fmaxf(c, 0.0f);
            h_s[4 * quad + r][16 * w + l16] = f2bf(h);
        }
        __syncthreads();
        // publish h-slice (2KB) + write hcat output. batch stride in hbuf = 64 u64.
        unsigned long long hv = *reinterpret_cast<unsigned long long*>(&h_s[hb_b][hb_ch * 4]);
        unsigned long long* dst = ((t & 1) ? hb1 : hb0) + hb_b * 64 + sl * 16 + hb_ch;
        __hip_atomic_store(dst, hv, __ATOMIC_RELAXED, __HIP_MEMORY_SCOPE_AGENT);
        *reinterpret_cast<unsigned long long*>(hcat16 + hcat_base + (long)s * 512) = hv;
        __syncthreads();   // compiler emits s_waitcnt vmcnt(0) before s_barrier: stores complete
        if (tid == 0)
            __hip_atomic_fetch_add(&myctr[t], 1u, __ATOMIC_RELAXED, __HIP_MEMORY_SCOPE_AGENT);
    }
}

// ---------------- K3: logits = hcat @ Wd  (MFMA, N padded to 64) ------------
__global__ __launch_bounds__(256) void k_gemm_logits(
    const unsigned short* __restrict__ hcat16, const unsigned short* __restrict__ WdT16,
    float* __restrict__ logits) {
    int w = threadIdx.x >> 6, lane = threadIdx.x & 63;
    int quad = lane >> 4, l16 = lane & 15;
    int m0 = blockIdx.x * 128 + w * 32;
    f32x4 acc[2][4];
#pragma unroll
    for (int mt = 0; mt < 2; ++mt)
#pragma unroll
        for (int nt = 0; nt < 4; ++nt) acc[mt][nt] = (f32x4){0.f, 0.f, 0.f, 0.f};
#pragma unroll
    for (int ks = 0; ks < 16; ++ks) {
        int k0 = ks * 32 + quad * 8;
        bf16x8 a[2], bb[4];
#pragma unroll
        for (int mt = 0; mt < 2; ++mt)
            a[mt] = ldb8(hcat16 + (long)(m0 + mt * 16 + l16) * 512 + k0);
#pragma unroll
        for (int nt = 0; nt < 4; ++nt)
            bb[nt] = ldb8(WdT16 + (long)(nt * 16 + l16) * 512 + k0);
#pragma unroll
        for (int mt = 0; mt < 2; ++mt)
#pragma unroll
            for (int nt = 0; nt < 4; ++nt)
                acc[mt][nt] = __builtin_amdgcn_mfma_f32_16x16x32_bf16(a[mt], bb[nt], acc[mt][nt], 0, 0, 0);
    }
#pragma unroll
    for (int mt = 0; mt < 2; ++mt)
#pragma unroll
        for (int nt = 0; nt < 4; ++nt) {
            int rbase = m0 + mt * 16 + quad * 4;
            int col = nt * 16 + l16;
#pragma unroll
            for (int r = 0; r < 4; ++r)
                logits[(long)(rbase + r) * 64 + col] = acc[mt][nt][r];
        }
}

// ---------------- K4: +bd, softmax over 50 tags (one wave per row) ----------
__global__ __launch_bounds__(256) void k_softmax(const float* __restrict__ logits,
                                                 const float* __restrict__ bd,
                                                 float* __restrict__ out) {
    int w = threadIdx.x >> 6, lane = threadIdx.x & 63;
    long r = (long)blockIdx.x * 4 + w;
    float x = (lane < TAGS_) ? logits[r * 64 + lane] + bd[lane] : -3.0e38f;
    float m = x;
#pragma unroll
    for (int off = 32; off >= 1; off >>= 1) m = fmaxf(m, __shfl_xor(m, off, 64));
    float e = (lane < TAGS_) ? __expf(x - m) : 0.0f;
    float ssum = e;
#pragma unroll
    for (int off = 32; off >= 1; off >>= 1) ssum += __shfl_xor(ssum, off, 64);
    if (lane < TAGS_) out[r * TAGS_ + lane] = e / ssum;
}

extern "C" void kernel_launch(void* const* d_in, const int* in_sizes, int n_in,
                              void* d_out, int out_size, void* d_ws, size_t ws_size,
                              hipStream_t stream) {
    (void)in_sizes; (void)n_in; (void)out_size; (void)ws_size;
    const int*   tokens = (const int*)  d_in[0];
    const float* emb    = (const float*)d_in[1];
    const float* Wx_f   = (const float*)d_in[2];
    const float* Wh_f   = (const float*)d_in[3];
    const float* b_f    = (const float*)d_in[4];
    const float* Wx_b   = (const float*)d_in[5];
    const float* Wh_b   = (const float*)d_in[6];
    const float* b_b    = (const float*)d_in[7];
    const float* Wd     = (const float*)d_in[8];
    const float* bd     = (const float*)d_in[9];
    float* out = (float*)d_out;

    // workspace layout (bytes): total 190,119,936
    uint8_t* w = (uint8_t*)d_ws;
    unsigned short* X16    = (unsigned short*)(w);                  // 20,971,520 (dead after K1)
    // aliases inside X16's region, used only after K1:
    unsigned short* WhP    = (unsigned short*)(w);                  //  1,048,576
    unsigned long long* hbuf = (unsigned long long*)(w + 1048576);  //    262,144
    unsigned int*   ctr    = (unsigned int*)(w + 1310720);          //     65,536
    unsigned short* W16T   = (unsigned short*)(w + 20971520);       //  1,310,720
    unsigned short* WdT16  = (unsigned short*)(w + 22282240);       //     65,536
    unsigned long long* xzP = (unsigned long long*)(w + 22347776);  // 134,217,728
    unsigned short* hcat16 = (unsigned short*)(w + 156565504);      //  33,554,432
    float*          logits = (float*)(w + 22347776);                // alias xzP (dead after K2)

    k_gather_x  <<<dim3(NROWS),     dim3(KPAD), 0, stream>>>(tokens, emb, X16);
    k_prep_w    <<<dim3(NCOLS),     dim3(KPAD), 0, stream>>>(Wx_f, Wx_b, W16T);
    k_prep_wd   <<<dim3(64),        dim3(512),  0, stream>>>(Wd, WdT16);
    k_gemm_xz   <<<dim3(256, 16),   dim3(256),  0, stream>>>(X16, W16T, b_f, b_b, xzP);
    // X16 region now dead -> build WhP / hbuf / ctr in it
    k_prep_wh   <<<dim3(2048),      dim3(256),  0, stream>>>(Wh_f, Wh_b, WhP);
    k_zero      <<<dim3(16),        dim3(256),  0, stream>>>(ctr);
    k_recurrence<<<dim3(64),        dim3(256),  0, stream>>>(WhP, xzP, hcat16, hbuf, ctr);
    k_gemm_logits<<<dim3(256),      dim3(256),  0, stream>>>(hcat16, WdT16, logits);
    k_softmax   <<<dim3(NROWS / 4), dim3(256),  0, stream>>>(logits, bd, out);
}